// Round 12
// baseline (555.507 us; speedup 1.0000x reference)
//
#include <hip/hip_runtime.h>

#define HID 32
#define NATOMS 250000
#define NPAIRS 4000000
#define MAXNEI 16
#define NMOL 2000
#define MAXATOMS 128
#define FEAT 8

typedef unsigned short ushort_t;
typedef unsigned int uint_t;
typedef short bf16x8 __attribute__((ext_vector_type(8)));
typedef float f32x4 __attribute__((ext_vector_type(4)));

__device__ __forceinline__ float sigmoidf_(float x) { return 1.f / (1.f + __expf(-x)); }
__device__ __forceinline__ float tanhfast_(float x) {
    float e = __expf(2.f * x);
    return 1.f - 2.f / (e + 1.f);
}
__device__ __forceinline__ ushort_t f2bf(float f) {   // RNE
    uint_t u = __float_as_uint(f);
    u = (u + 0x7fffu + ((u >> 16) & 1u)) >> 16;
    return (ushort_t)u;
}
__device__ __forceinline__ float bf2f(ushort_t h) { return __uint_as_float((uint_t)h << 16); }
__device__ __forceinline__ float bflo(uint_t w) { return __uint_as_float(w << 16); }
__device__ __forceinline__ float bfhi(uint_t w) { return __uint_as_float(w & 0xffff0000u); }
// split x into hi+lo bf16 pair (16 effective mantissa bits)
__device__ __forceinline__ void splitbf(float x, short& hi, short& lo) {
    ushort_t h = f2bf(x);
    hi = (short)h;
    lo = (short)f2bf(x - bf2f(h));
}

// ---------- prep: 32B packed record {8xbf16 feats, f32 rij, su, sul, pad} ----------
__global__ __launch_bounds__(256) void k_prep32(
        const float* __restrict__ fdg, const float* __restrict__ rij,
        const int* __restrict__ su, const int* __restrict__ sul,
        uint4* __restrict__ rec) {
    int p = blockIdx.x * 256 + threadIdx.x;   // grid NPAIRS/256 exact
    const float4* f4 = (const float4*)(fdg + (size_t)p * FEAT);
    float4 a = f4[0], b = f4[1];
    uint4 lo;
    lo.x = (uint_t)f2bf(a.x) | ((uint_t)f2bf(a.y) << 16);
    lo.y = (uint_t)f2bf(a.z) | ((uint_t)f2bf(a.w) << 16);
    lo.z = (uint_t)f2bf(b.x) | ((uint_t)f2bf(b.y) << 16);
    lo.w = (uint_t)f2bf(b.z) | ((uint_t)f2bf(b.w) << 16);
    uint4 hi = make_uint4(__float_as_uint(rij[p]), (uint_t)su[p], (uint_t)sul[p], 0u);
    rec[(size_t)p * 2] = lo;
    rec[(size_t)p * 2 + 1] = hi;
}

// ---------- prep: split GRU weights into MFMA B-frag hi/lo planes ----------
__global__ __launch_bounds__(256) void k_prep_w(
        const float* __restrict__ gWz, const float* __restrict__ gWr,
        const float* __restrict__ gWh, ushort_t* __restrict__ wsplit) {
    int t = blockIdx.x * 256 + threadIdx.x;
    if (t >= 36 * 64) return;
    int lane = t & 63;
    int fi = t >> 6;              // 0..35
    int kstep = fi & 1;
    int nt = (fi >> 1) & 1;
    int mat = (fi >> 2) % 3;
    int d = fi / 12;
    const float* W = (mat == 0) ? gWz : (mat == 1) ? gWr : gWh;
    W += d * 2 * HID * HID;
    int g = lane >> 4, cl = lane & 15;
    ushort_t hi8[8], lo8[8];
#pragma unroll
    for (int m = 0; m < 8; m++) {
        float w = W[(kstep * 32 + g * 8 + m) * HID + nt * 16 + cl];
        short th, tl;
        splitbf(w, th, tl);
        hi8[m] = (ushort_t)th;
        lo8[m] = (ushort_t)tl;
    }
    ushort_t* dh = wsplit + ((size_t)fi * 2 + 0) * 512 + lane * 8;
    ushort_t* dl = wsplit + ((size_t)fi * 2 + 1) * 512 + lane * 8;
#pragma unroll
    for (int m = 0; m < 8; m++) { dh[m] = hi8[m]; dl[m] = lo8[m]; }
}

// h0 = tf@Wia ; agg0 = (sum relu(edge@Wib))@Wh ; builds srcs.
// 4 atoms per 32-lane group (lane owns slot n of atoms ja and ja+2) ->
// 4 independent rec-pair gathers in flight per lane. 48B-stride f32 LDS rows
// (conflict-free), zero-filled when invalid (relu self-masks).
__global__ __launch_bounds__(256) void k_init_rec(
        const float* __restrict__ tf, const int* __restrict__ bsc,
        const uint4* __restrict__ rec,
        const float* __restrict__ Wia, const float* __restrict__ Wib,
        const float* __restrict__ Wh,
        float* __restrict__ h, float* __restrict__ agg,
        int* __restrict__ srcs, ushort_t* __restrict__ hbf) {
    __shared__ float lbuf[8][4][MAXNEI][12];   // 24 KB/block
    int grp = threadIdx.x >> 5;
    int j = threadIdx.x & 31;
    int ja = j >> 4;              // 0..1
    int n = j & 15;
    int gid0 = (blockIdx.x * 8 + grp) * 4;     // grid 7813: tail predicated

    int at0 = gid0 + ja;          // this lane's slot atoms
    int at1 = gid0 + ja + 2;
    int ca0 = min(at0, NATOMS - 1);
    int ca1 = min(at1, NATOMS - 1);

    int idx0 = bsc[ca0 * MAXNEI + n];
    int idx1 = bsc[ca1 * MAXNEI + n];
    int p0 = (idx0 > 0) ? (idx0 - 1) : 0;
    int p1 = (idx1 > 0) ? (idx1 - 1) : 0;
    bool v0 = (idx0 > 0), v1 = (idx1 > 0);

    uint4 lo0 = rec[(size_t)p0 * 2];
    uint4 hi0 = rec[(size_t)p0 * 2 + 1];
    uint4 lo1 = rec[(size_t)p1 * 2];
    uint4 hi1 = rec[(size_t)p1 * 2 + 1];

    if (at0 < NATOMS) {
        srcs[(size_t)at0 * 32 + n]      = v0 ? (int)hi0.y : NATOMS;
        srcs[(size_t)at0 * 32 + 16 + n] = v0 ? (int)hi0.z : NATOMS;
    }
    if (at1 < NATOMS) {
        srcs[(size_t)at1 * 32 + n]      = v1 ? (int)hi1.y : NATOMS;
        srcs[(size_t)at1 * 32 + 16 + n] = v1 ? (int)hi1.z : NATOMS;
    }
    if (blockIdx.x == 0 && threadIdx.x < HID)
        hbf[(size_t)NATOMS * HID + threadIdx.x] = 0;

    if (!v0) { lo0 = make_uint4(0u, 0u, 0u, 0u); hi0.x = 0u; }
    if (!v1) { lo1 = make_uint4(0u, 0u, 0u, 0u); hi1.x = 0u; }

    {
        float* r0 = lbuf[grp][ja][n];
        r0[0] = bflo(lo0.x); r0[1] = bfhi(lo0.x);
        r0[2] = bflo(lo0.y); r0[3] = bfhi(lo0.y);
        r0[4] = bflo(lo0.z); r0[5] = bfhi(lo0.z);
        r0[6] = bflo(lo0.w); r0[7] = bfhi(lo0.w);
        r0[8] = __uint_as_float(hi0.x);
        float* r1 = lbuf[grp][ja + 2][n];
        r1[0] = bflo(lo1.x); r1[1] = bfhi(lo1.x);
        r1[2] = bflo(lo1.y); r1[3] = bfhi(lo1.y);
        r1[4] = bflo(lo1.z); r1[5] = bfhi(lo1.z);
        r1[6] = bflo(lo1.w); r1[7] = bfhi(lo1.w);
        r1[8] = __uint_as_float(hi1.x);
    }

    float wib[9];
#pragma unroll
    for (int k = 0; k < 9; k++) wib[k] = Wib[k * HID + j];

    // h0 rows for the 4 atoms (lane-uniform tf reads, broadcast)
    float hj[4];
#pragma unroll
    for (int a = 0; a < 4; a++) {
        int ca = min(gid0 + a, NATOMS - 1);
        float acc = 0.f;
#pragma unroll
        for (int k = 0; k < FEAT; k++)
            acc = fmaf(tf[(size_t)ca * FEAT + k], Wia[k * HID + j], acc);
        hj[a] = acc;
    }

    __syncthreads();   // all 256 threads always reach

    float aggE[4];
#pragma unroll
    for (int a = 0; a < 4; a++) {
        float e = 0.f;
#pragma unroll
        for (int nn = 0; nn < MAXNEI; nn++) {
            const float* r = lbuf[grp][a][nn];
            float acc = r[8] * wib[8];
#pragma unroll
            for (int k = 0; k < FEAT; k++) acc = fmaf(r[k], wib[k], acc);
            e += fmaxf(acc, 0.f);
        }
        aggE[a] = e;
    }

    float o[4] = {0.f, 0.f, 0.f, 0.f};
#pragma unroll
    for (int k = 0; k < HID; k++) {
        float wv = Wh[k * HID + j];
#pragma unroll
        for (int a = 0; a < 4; a++)
            o[a] = fmaf(__shfl(aggE[a], k, 32), wv, o[a]);
    }
#pragma unroll
    for (int a = 0; a < 4; a++) {
        int gid = gid0 + a;
        if (gid < NATOMS) {
            h[(size_t)gid * HID + j] = hj[a];
            agg[(size_t)gid * HID + j] = o[a];
        }
    }
}

// ---------- MFMA GRU, split-bf16 (hi+lo), single C-layout h read ----------
// A layout: lane l holds A[row=l&15][cols 8*(l>>4)..+7]
// B layout: lane l holds B[rows 8*(l>>4)..+7][col=l&15]
// C layout: lane l reg q -> row (l>>4)*4+q, col l&15   [m89-verified]
__global__ __launch_bounds__(256) void k_gru_mfma(
        float* __restrict__ h, ushort_t* __restrict__ hbf,
        const float* __restrict__ agg, const ushort_t* __restrict__ wsp,
        const float* __restrict__ bz, const float* __restrict__ br,
        const float* __restrict__ bh) {
    __shared__ float hlds[4][16][36];    // fp32 h C->A relayout
    __shared__ float rhlds[4][16][36];   // fp32 r*h relayout
    int wid = threadIdx.x >> 6;
    int l = threadIdx.x & 63;
    int g = l >> 4;                // 0..3
    int cl = l & 15;               // 0..15
    int A0 = blockIdx.x * 64 + wid * 16;

    // --- agg A-frags (coalesced global), split hi/lo ---
    int rowA = min(A0 + cl, NATOMS - 1);
    const float4* ap = (const float4*)(agg + (size_t)rowA * HID + g * 8);
    float4 fa0 = ap[0], fa1 = ap[1];
    bf16x8 a0h, a0l;
    {
        float av[8] = {fa0.x, fa0.y, fa0.z, fa0.w, fa1.x, fa1.y, fa1.z, fa1.w};
#pragma unroll
        for (int m = 0; m < 8; m++) {
            short th, tl;
            splitbf(av[m], th, tl); a0h[m] = th; a0l[m] = tl;
        }
    }

    // --- h in C layout (single global read), stage to LDS for A-frags ---
    int rowC = A0 + g * 4;
    float hC[4][2];
#pragma unroll
    for (int q = 0; q < 4; q++) {
        int r = min(rowC + q, NATOMS - 1);
#pragma unroll
        for (int nt = 0; nt < 2; nt++) {
            hC[q][nt] = h[(size_t)r * HID + nt * 16 + cl];
            hlds[wid][g * 4 + q][nt * 16 + cl] = hC[q][nt];
        }
    }
    asm volatile("s_waitcnt lgkmcnt(0)" ::: "memory");
    __builtin_amdgcn_sched_barrier(0);

    bf16x8 a1h, a1l;
    {
        float4 r0 = *(const float4*)&hlds[wid][cl][g * 8];
        float4 r1 = *(const float4*)&hlds[wid][cl][g * 8 + 4];
        float hv[8] = {r0.x, r0.y, r0.z, r0.w, r1.x, r1.y, r1.z, r1.w};
#pragma unroll
        for (int m = 0; m < 8; m++) {
            short th, tl;
            splitbf(hv[m], th, tl); a1h[m] = th; a1l[m] = tl;
        }
    }

    // --- pre-split B-frag loads: fi = mat*4 + nt*2 + kstep ---
#define LOADW(mat, nt, kstep, dh, dl) { \
        int fi_ = (mat) * 4 + (nt) * 2 + (kstep); \
        dh = *(const bf16x8*)(wsp + ((size_t)fi_ * 2 + 0) * 512 + l * 8); \
        dl = *(const bf16x8*)(wsp + ((size_t)fi_ * 2 + 1) * 512 + l * 8); }
    // 3-product split matmul: ah@bh + ah@bl + al@bh  (~fp32 precision)
#define MM3(ah, al, bh, bl, acc) { \
        acc = __builtin_amdgcn_mfma_f32_16x16x32_bf16(ah, bh, acc, 0, 0, 0); \
        acc = __builtin_amdgcn_mfma_f32_16x16x32_bf16(ah, bl, acc, 0, 0, 0); \
        acc = __builtin_amdgcn_mfma_f32_16x16x32_bf16(al, bh, acc, 0, 0, 0); }

    f32x4 zacc[2], racc[2];
#pragma unroll
    for (int nt = 0; nt < 2; nt++) {
        bf16x8 b0h, b0l, b1h, b1l;
        LOADW(0, nt, 0, b0h, b0l); LOADW(0, nt, 1, b1h, b1l);
        f32x4 acc = {0.f, 0.f, 0.f, 0.f};
        MM3(a0h, a0l, b0h, b0l, acc);
        MM3(a1h, a1l, b1h, b1l, acc);
        zacc[nt] = acc;
        LOADW(1, nt, 0, b0h, b0l); LOADW(1, nt, 1, b1h, b1l);
        f32x4 acc2 = {0.f, 0.f, 0.f, 0.f};
        MM3(a0h, a0l, b0h, b0l, acc2);
        MM3(a1h, a1l, b1h, b1l, acc2);
        racc[nt] = acc2;
    }

    float z[4][2];
#pragma unroll
    for (int nt = 0; nt < 2; nt++) {
        float bzv = bz[nt * 16 + cl];
        float brv = br[nt * 16 + cl];
#pragma unroll
        for (int q = 0; q < 4; q++) {
            z[q][nt] = sigmoidf_(zacc[nt][q] + bzv);
            float rv = sigmoidf_(racc[nt][q] + brv);
            rhlds[wid][g * 4 + q][nt * 16 + cl] = rv * hC[q][nt];   // fp32
        }
    }

    asm volatile("s_waitcnt lgkmcnt(0)" ::: "memory");
    __builtin_amdgcn_sched_barrier(0);

    bf16x8 a2h, a2l;
    {
        float4 r0 = *(const float4*)&rhlds[wid][cl][g * 8];
        float4 r1 = *(const float4*)&rhlds[wid][cl][g * 8 + 4];
        float rv[8] = {r0.x, r0.y, r0.z, r0.w, r1.x, r1.y, r1.z, r1.w};
#pragma unroll
        for (int m = 0; m < 8; m++) {
            short th, tl;
            splitbf(rv[m], th, tl); a2h[m] = th; a2l[m] = tl;
        }
    }

    f32x4 hcacc[2];
#pragma unroll
    for (int nt = 0; nt < 2; nt++) {
        bf16x8 b0h, b0l, b1h, b1l;
        LOADW(2, nt, 0, b0h, b0l); LOADW(2, nt, 1, b1h, b1l);
        f32x4 acc = {0.f, 0.f, 0.f, 0.f};
        MM3(a0h, a0l, b0h, b0l, acc);
        MM3(a2h, a2l, b1h, b1l, acc);
        hcacc[nt] = acc;
    }
#undef LOADW
#undef MM3

#pragma unroll
    for (int nt = 0; nt < 2; nt++) {
        float bhv = bh[nt * 16 + cl];
#pragma unroll
        for (int q = 0; q < 4; q++) {
            int r = rowC + q;
            if (r < NATOMS) {
                float hc = tanhfast_(hcacc[nt][q] + bhv);
                float zz = z[q][nt];
                float hn = (1.f - zz) * hC[q][nt] + zz * hc;
                h[(size_t)r * HID + nt * 16 + cl] = hn;
                if (hbf) hbf[(size_t)r * HID + nt * 16 + cl] = f2bf(hn);
            }
        }
    }
}

// agg = (sum of 32 gathered bf16 h rows) @ Wh. 4 atoms per 32-lane group,
// 8 groups per 256-thread block.
__global__ __launch_bounds__(256) void k_agg4(
        const ushort_t* __restrict__ hbf, const int* __restrict__ srcs,
        const float* __restrict__ Wh, float* __restrict__ agg) {
    int grp = threadIdx.x >> 5;
    int j = threadIdx.x & 31;
    int gid0 = (blockIdx.x * 8 + grp) * 4;
    if (gid0 >= NATOMS) return;   // no __syncthreads in kernel

    int s[4];
#pragma unroll
    for (int a = 0; a < 4; a++) s[a] = srcs[(size_t)(gid0 + a) * 32 + j];

    int rslot = j >> 2;
    int c = j & 3;

    uint4 v[4][4];
#pragma unroll
    for (int a = 0; a < 4; a++)
#pragma unroll
        for (int sw = 0; sw < 4; sw++) {
            int r = __shfl(s[a], sw * 8 + rslot, 32);
            v[a][sw] = ((const uint4*)(hbf + (size_t)r * HID))[c];
        }

    float acc[4][8];
#pragma unroll
    for (int a = 0; a < 4; a++)
#pragma unroll
        for (int e = 0; e < 8; e++) acc[a][e] = 0.f;
#pragma unroll
    for (int a = 0; a < 4; a++)
#pragma unroll
        for (int sw = 0; sw < 4; sw++) {
            const uint_t* u = (const uint_t*)&v[a][sw];
#pragma unroll
            for (int e = 0; e < 8; e++)
                acc[a][e] += (e & 1) ? bfhi(u[e >> 1]) : bflo(u[e >> 1]);
        }
#pragma unroll
    for (int m = 4; m <= 16; m <<= 1)
#pragma unroll
        for (int a = 0; a < 4; a++)
#pragma unroll
            for (int e = 0; e < 8; e++) acc[a][e] += __shfl_xor(acc[a][e], m, 32);

    float o[4] = {0.f, 0.f, 0.f, 0.f};
#pragma unroll
    for (int k = 0; k < HID; k++) {
        float wv = Wh[k * HID + j];
#pragma unroll
        for (int a = 0; a < 4; a++)
            o[a] = fmaf(__shfl(acc[a][k & 7], k >> 3, 32), wv, o[a]);
    }
#pragma unroll
    for (int a = 0; a < 4; a++) agg[(size_t)(gid0 + a) * HID + j] = o[a];
}

__global__ __launch_bounds__(256) void k_mol(
        const float* __restrict__ h, const int* __restrict__ lsc,
        float* __restrict__ out) {
    int m = blockIdx.x;
    int g = threadIdx.x >> 5;
    int j = threadIdx.x & 31;
    float acc = 0.f;
    for (int i = g; i < MAXATOMS; i += 8) {
        int idx = lsc[m * MAXATOMS + i];
        if (idx > 0) acc += h[(size_t)(idx - 1) * HID + j];
    }
    __shared__ float red[8][33];
    red[g][j] = acc;
    __syncthreads();
    if (g == 0) {
        float s = red[0][j] + red[1][j] + red[2][j] + red[3][j]
                + red[4][j] + red[5][j] + red[6][j] + red[7][j];
        out[m * HID + j] = s;
    }
}

extern "C" void kernel_launch(void* const* d_in, const int* in_sizes, int n_in,
                              void* d_out, int out_size, void* d_ws, size_t ws_size,
                              hipStream_t stream) {
    (void)in_sizes; (void)n_in; (void)out_size; (void)ws_size;
    const float* tf  = (const float*)d_in[0];
    const float* fdg = (const float*)d_in[1];
    const float* rij = (const float*)d_in[2];
    const int*   bsc = (const int*)d_in[3];
    const int*   lsc = (const int*)d_in[4];
    const int*   su  = (const int*)d_in[5];
    const int*   sul = (const int*)d_in[6];
    const float* Wia = (const float*)d_in[7];
    const float* Wib = (const float*)d_in[8];
    const float* Wh  = (const float*)d_in[9];
    const float* gWz = (const float*)d_in[10];
    const float* gWr = (const float*)d_in[11];
    const float* gWh = (const float*)d_in[12];
    const float* gbz = (const float*)d_in[13];
    const float* gbr = (const float*)d_in[14];
    const float* gbh = (const float*)d_in[15];
    float* out = (float*)d_out;

    char* ws = (char*)d_ws;
    const size_t HBYTES = (size_t)NATOMS * HID * 4;                   // 32 MB
    const size_t WSPLITB = 36 * 2 * 512 * 2;                          // 72 KB
    const size_t HBFBYTES = ((size_t)(NATOMS + 1) * HID * 2 + 255) & ~(size_t)255;
    const size_t SRCSBYTES = (size_t)NATOMS * 32 * 4;                 // 32 MB
    float* h   = (float*)ws;
    float* agg = (float*)(ws + HBYTES);
    ushort_t* wsplit = (ushort_t*)(ws + 2 * HBYTES);
    ushort_t* hbf = (ushort_t*)(ws + 2 * HBYTES + WSPLITB);
    int* srcs = (int*)(ws + 2 * HBYTES + WSPLITB + HBFBYTES);
    uint4* rec = (uint4*)(ws + 2 * HBYTES + WSPLITB + HBFBYTES + SRCSBYTES);

    dim3 igrid((NATOMS + 31) / 32);            // 7813 (4 atoms/group, 8 groups)
    dim3 ggrid((NATOMS + 63) / 64);            // 3907
    dim3 agrid((NATOMS / 4 + 7) / 8);          // 7813

    k_prep32<<<NPAIRS / 256, 256, 0, stream>>>(fdg, rij, su, sul, rec);
    k_prep_w<<<9, 256, 0, stream>>>(gWz, gWr, gWh, wsplit);
    k_init_rec<<<igrid, 256, 0, stream>>>(tf, bsc, rec, Wia, Wib, Wh,
                                          h, agg, srcs, hbf);

    for (int d = 0; d < 3; d++) {
        ushort_t* hbf_w = (d < 2) ? hbf : nullptr;
        k_gru_mfma<<<ggrid, 256, 0, stream>>>(
            h, hbf_w, agg, wsplit + (size_t)d * 12288,
            gbz + d * HID, gbr + d * HID, gbh + d * HID);
        if (d < 2)
            k_agg4<<<agrid, 256, 0, stream>>>(hbf, srcs, Wh, agg);
    }
    k_mol<<<NMOL, 256, 0, stream>>>(h, lsc, out);
}

// Round 13
// 499.743 us; speedup vs baseline: 1.1116x; 1.1116x over previous
//
#include <hip/hip_runtime.h>

#define HID 32
#define NATOMS 250000
#define NPAIRS 4000000
#define MAXNEI 16
#define NMOL 2000
#define MAXATOMS 128
#define FEAT 8

typedef unsigned short ushort_t;
typedef unsigned int uint_t;
typedef short bf16x8 __attribute__((ext_vector_type(8)));
typedef float f32x4 __attribute__((ext_vector_type(4)));

__device__ __forceinline__ float sigmoidf_(float x) { return 1.f / (1.f + __expf(-x)); }
__device__ __forceinline__ float tanhfast_(float x) {
    float e = __expf(2.f * x);
    return 1.f - 2.f / (e + 1.f);
}
__device__ __forceinline__ ushort_t f2bf(float f) {   // RNE
    uint_t u = __float_as_uint(f);
    u = (u + 0x7fffu + ((u >> 16) & 1u)) >> 16;
    return (ushort_t)u;
}
__device__ __forceinline__ float bf2f(ushort_t h) { return __uint_as_float((uint_t)h << 16); }
__device__ __forceinline__ float bflo(uint_t w) { return __uint_as_float(w << 16); }
__device__ __forceinline__ float bfhi(uint_t w) { return __uint_as_float(w & 0xffff0000u); }
// split x into hi+lo bf16 pair (16 effective mantissa bits)
__device__ __forceinline__ void splitbf(float x, short& hi, short& lo) {
    ushort_t h = f2bf(x);
    hi = (short)h;
    lo = (short)f2bf(x - bf2f(h));
}

// ---------- prep: 32B packed record {8xbf16 feats, f32 rij, su, sul, pad} ----------
__global__ __launch_bounds__(256) void k_prep32(
        const float* __restrict__ fdg, const float* __restrict__ rij,
        const int* __restrict__ su, const int* __restrict__ sul,
        uint4* __restrict__ rec) {
    int p = blockIdx.x * 256 + threadIdx.x;   // grid NPAIRS/256 exact
    const float4* f4 = (const float4*)(fdg + (size_t)p * FEAT);
    float4 a = f4[0], b = f4[1];
    uint4 lo;
    lo.x = (uint_t)f2bf(a.x) | ((uint_t)f2bf(a.y) << 16);
    lo.y = (uint_t)f2bf(a.z) | ((uint_t)f2bf(a.w) << 16);
    lo.z = (uint_t)f2bf(b.x) | ((uint_t)f2bf(b.y) << 16);
    lo.w = (uint_t)f2bf(b.z) | ((uint_t)f2bf(b.w) << 16);
    uint4 hi = make_uint4(__float_as_uint(rij[p]), (uint_t)su[p], (uint_t)sul[p], 0u);
    rec[(size_t)p * 2] = lo;
    rec[(size_t)p * 2 + 1] = hi;
}

// ---------- prep: split GRU weights into MFMA B-frag hi/lo planes ----------
__global__ __launch_bounds__(256) void k_prep_w(
        const float* __restrict__ gWz, const float* __restrict__ gWr,
        const float* __restrict__ gWh, ushort_t* __restrict__ wsplit) {
    int t = blockIdx.x * 256 + threadIdx.x;
    if (t >= 36 * 64) return;
    int lane = t & 63;
    int fi = t >> 6;              // 0..35
    int kstep = fi & 1;
    int nt = (fi >> 1) & 1;
    int mat = (fi >> 2) % 3;
    int d = fi / 12;
    const float* W = (mat == 0) ? gWz : (mat == 1) ? gWr : gWh;
    W += d * 2 * HID * HID;
    int g = lane >> 4, cl = lane & 15;
    ushort_t hi8[8], lo8[8];
#pragma unroll
    for (int m = 0; m < 8; m++) {
        float w = W[(kstep * 32 + g * 8 + m) * HID + nt * 16 + cl];
        short th, tl;
        splitbf(w, th, tl);
        hi8[m] = (ushort_t)th;
        lo8[m] = (ushort_t)tl;
    }
    ushort_t* dh = wsplit + ((size_t)fi * 2 + 0) * 512 + lane * 8;
    ushort_t* dl = wsplit + ((size_t)fi * 2 + 1) * 512 + lane * 8;
#pragma unroll
    for (int m = 0; m < 8; m++) { dh[m] = hi8[m]; dl[m] = lo8[m]; }
}

// h0 = tf@Wia ; agg0 = (sum relu(edge@Wib))@Wh from 32B records; builds srcs.
// 2 atoms per 32-lane group, 8 groups/block (round-10 structure: 28 VGPR,
// 82% occupancy, conflict-free 48B-stride LDS rows).
__global__ __launch_bounds__(256) void k_init_rec(
        const float* __restrict__ tf, const int* __restrict__ bsc,
        const uint4* __restrict__ rec,
        const float* __restrict__ Wia, const float* __restrict__ Wib,
        const float* __restrict__ Wh,
        float* __restrict__ h, float* __restrict__ agg,
        int* __restrict__ srcs, ushort_t* __restrict__ hbf) {
    __shared__ float lbuf[8][2][MAXNEI][12];
    int grp = threadIdx.x >> 5;
    int j = threadIdx.x & 31;
    int ja = j >> 4;
    int n = j & 15;
    int gid0 = (blockIdx.x * 8 + grp) * 2;
    int gidja = gid0 + ja;

    int myidx = bsc[gidja * MAXNEI + n];
    int p = (myidx > 0) ? (myidx - 1) : 0;
    float valid = (myidx > 0) ? 1.f : 0.f;

    uint4 lo = rec[(size_t)p * 2];
    uint4 hi = rec[(size_t)p * 2 + 1];

    srcs[(size_t)gidja * 32 + n]      = (myidx > 0) ? (int)hi.y : NATOMS;
    srcs[(size_t)gidja * 32 + 16 + n] = (myidx > 0) ? (int)hi.z : NATOMS;
    if (blockIdx.x == 0 && threadIdx.x < HID)
        hbf[(size_t)NATOMS * HID + threadIdx.x] = 0;

    float* row = lbuf[grp][ja][n];
    row[0] = bflo(lo.x); row[1] = bfhi(lo.x);
    row[2] = bflo(lo.y); row[3] = bfhi(lo.y);
    row[4] = bflo(lo.z); row[5] = bfhi(lo.z);
    row[6] = bflo(lo.w); row[7] = bfhi(lo.w);
    row[8] = __uint_as_float(hi.x);
    row[9] = valid;

    float wib[9];
#pragma unroll
    for (int k = 0; k < 9; k++) wib[k] = Wib[k * HID + j];

    float hj0 = 0.f, hj1 = 0.f;
#pragma unroll
    for (int k = 0; k < FEAT; k++) {
        hj0 = fmaf(tf[(size_t)gid0 * FEAT + k], Wia[k * HID + j], hj0);
        hj1 = fmaf(tf[(size_t)(gid0 + 1) * FEAT + k], Wia[k * HID + j], hj1);
    }

    __syncthreads();

    float aggE[2];
#pragma unroll
    for (int a = 0; a < 2; a++) {
        float e = 0.f;
#pragma unroll
        for (int nn = 0; nn < MAXNEI; nn++) {
            const float* r = lbuf[grp][a][nn];
            float acc = r[8] * wib[8];
#pragma unroll
            for (int k = 0; k < FEAT; k++) acc = fmaf(r[k], wib[k], acc);
            e += r[9] * fmaxf(acc, 0.f);
        }
        aggE[a] = e;
    }

    float o0 = 0.f, o1 = 0.f;
#pragma unroll
    for (int k = 0; k < HID; k++) {
        float wv = Wh[k * HID + j];
        o0 = fmaf(__shfl(aggE[0], k, 32), wv, o0);
        o1 = fmaf(__shfl(aggE[1], k, 32), wv, o1);
    }
    h[(size_t)gid0 * HID + j] = hj0;
    h[(size_t)(gid0 + 1) * HID + j] = hj1;
    agg[(size_t)gid0 * HID + j] = o0;
    agg[(size_t)(gid0 + 1) * HID + j] = o1;
}

// ---------- MFMA GRU, split-bf16 (hi+lo), single C-layout h read ----------
// A layout: lane l holds A[row=l&15][cols 8*(l>>4)..+7]
// B layout: lane l holds B[rows 8*(l>>4)..+7][col=l&15]
// C layout: lane l reg q -> row (l>>4)*4+q, col l&15   [m89-verified]
__global__ __launch_bounds__(256) void k_gru_mfma(
        float* __restrict__ h, ushort_t* __restrict__ hbf,
        const float* __restrict__ agg, const ushort_t* __restrict__ wsp,
        const float* __restrict__ bz, const float* __restrict__ br,
        const float* __restrict__ bh) {
    __shared__ float hlds[4][16][36];    // fp32 h C->A relayout
    __shared__ float rhlds[4][16][36];   // fp32 r*h relayout
    int wid = threadIdx.x >> 6;
    int l = threadIdx.x & 63;
    int g = l >> 4;                // 0..3
    int cl = l & 15;               // 0..15
    int A0 = blockIdx.x * 64 + wid * 16;

    // --- agg A-frags (coalesced global), split hi/lo ---
    int rowA = min(A0 + cl, NATOMS - 1);
    const float4* ap = (const float4*)(agg + (size_t)rowA * HID + g * 8);
    float4 fa0 = ap[0], fa1 = ap[1];
    bf16x8 a0h, a0l;
    {
        float av[8] = {fa0.x, fa0.y, fa0.z, fa0.w, fa1.x, fa1.y, fa1.z, fa1.w};
#pragma unroll
        for (int m = 0; m < 8; m++) {
            short th, tl;
            splitbf(av[m], th, tl); a0h[m] = th; a0l[m] = tl;
        }
    }

    // --- h in C layout (single global read), stage to LDS for A-frags ---
    int rowC = A0 + g * 4;
    float hC[4][2];
#pragma unroll
    for (int q = 0; q < 4; q++) {
        int r = min(rowC + q, NATOMS - 1);
#pragma unroll
        for (int nt = 0; nt < 2; nt++) {
            hC[q][nt] = h[(size_t)r * HID + nt * 16 + cl];
            hlds[wid][g * 4 + q][nt * 16 + cl] = hC[q][nt];
        }
    }
    asm volatile("s_waitcnt lgkmcnt(0)" ::: "memory");
    __builtin_amdgcn_sched_barrier(0);

    bf16x8 a1h, a1l;
    {
        float4 r0 = *(const float4*)&hlds[wid][cl][g * 8];
        float4 r1 = *(const float4*)&hlds[wid][cl][g * 8 + 4];
        float hv[8] = {r0.x, r0.y, r0.z, r0.w, r1.x, r1.y, r1.z, r1.w};
#pragma unroll
        for (int m = 0; m < 8; m++) {
            short th, tl;
            splitbf(hv[m], th, tl); a1h[m] = th; a1l[m] = tl;
        }
    }

    // --- pre-split B-frag loads: fi = mat*4 + nt*2 + kstep ---
#define LOADW(mat, nt, kstep, dh, dl) { \
        int fi_ = (mat) * 4 + (nt) * 2 + (kstep); \
        dh = *(const bf16x8*)(wsp + ((size_t)fi_ * 2 + 0) * 512 + l * 8); \
        dl = *(const bf16x8*)(wsp + ((size_t)fi_ * 2 + 1) * 512 + l * 8); }
    // 3-product split matmul: ah@bh + ah@bl + al@bh  (~fp32 precision)
#define MM3(ah, al, bh, bl, acc) { \
        acc = __builtin_amdgcn_mfma_f32_16x16x32_bf16(ah, bh, acc, 0, 0, 0); \
        acc = __builtin_amdgcn_mfma_f32_16x16x32_bf16(ah, bl, acc, 0, 0, 0); \
        acc = __builtin_amdgcn_mfma_f32_16x16x32_bf16(al, bh, acc, 0, 0, 0); }

    f32x4 zacc[2], racc[2];
#pragma unroll
    for (int nt = 0; nt < 2; nt++) {
        bf16x8 b0h, b0l, b1h, b1l;
        LOADW(0, nt, 0, b0h, b0l); LOADW(0, nt, 1, b1h, b1l);
        f32x4 acc = {0.f, 0.f, 0.f, 0.f};
        MM3(a0h, a0l, b0h, b0l, acc);
        MM3(a1h, a1l, b1h, b1l, acc);
        zacc[nt] = acc;
        LOADW(1, nt, 0, b0h, b0l); LOADW(1, nt, 1, b1h, b1l);
        f32x4 acc2 = {0.f, 0.f, 0.f, 0.f};
        MM3(a0h, a0l, b0h, b0l, acc2);
        MM3(a1h, a1l, b1h, b1l, acc2);
        racc[nt] = acc2;
    }

    float z[4][2];
#pragma unroll
    for (int nt = 0; nt < 2; nt++) {
        float bzv = bz[nt * 16 + cl];
        float brv = br[nt * 16 + cl];
#pragma unroll
        for (int q = 0; q < 4; q++) {
            z[q][nt] = sigmoidf_(zacc[nt][q] + bzv);
            float rv = sigmoidf_(racc[nt][q] + brv);
            rhlds[wid][g * 4 + q][nt * 16 + cl] = rv * hC[q][nt];   // fp32
        }
    }

    asm volatile("s_waitcnt lgkmcnt(0)" ::: "memory");
    __builtin_amdgcn_sched_barrier(0);

    bf16x8 a2h, a2l;
    {
        float4 r0 = *(const float4*)&rhlds[wid][cl][g * 8];
        float4 r1 = *(const float4*)&rhlds[wid][cl][g * 8 + 4];
        float rv[8] = {r0.x, r0.y, r0.z, r0.w, r1.x, r1.y, r1.z, r1.w};
#pragma unroll
        for (int m = 0; m < 8; m++) {
            short th, tl;
            splitbf(rv[m], th, tl); a2h[m] = th; a2l[m] = tl;
        }
    }

    f32x4 hcacc[2];
#pragma unroll
    for (int nt = 0; nt < 2; nt++) {
        bf16x8 b0h, b0l, b1h, b1l;
        LOADW(2, nt, 0, b0h, b0l); LOADW(2, nt, 1, b1h, b1l);
        f32x4 acc = {0.f, 0.f, 0.f, 0.f};
        MM3(a0h, a0l, b0h, b0l, acc);
        MM3(a2h, a2l, b1h, b1l, acc);
        hcacc[nt] = acc;
    }
#undef LOADW
#undef MM3

#pragma unroll
    for (int nt = 0; nt < 2; nt++) {
        float bhv = bh[nt * 16 + cl];
#pragma unroll
        for (int q = 0; q < 4; q++) {
            int r = rowC + q;
            if (r < NATOMS) {
                float hc = tanhfast_(hcacc[nt][q] + bhv);
                float zz = z[q][nt];
                float hn = (1.f - zz) * hC[q][nt] + zz * hc;
                h[(size_t)r * HID + nt * 16 + cl] = hn;
                if (hbf) hbf[(size_t)r * HID + nt * 16 + cl] = f2bf(hn);
            }
        }
    }
}

// agg = (sum of 32 gathered bf16 h rows) @ Wh. 4 atoms per 32-lane group,
// 8 groups per 256-thread block.
__global__ __launch_bounds__(256) void k_agg4(
        const ushort_t* __restrict__ hbf, const int* __restrict__ srcs,
        const float* __restrict__ Wh, float* __restrict__ agg) {
    int grp = threadIdx.x >> 5;
    int j = threadIdx.x & 31;
    int gid0 = (blockIdx.x * 8 + grp) * 4;
    if (gid0 >= NATOMS) return;   // no __syncthreads in kernel

    int s[4];
#pragma unroll
    for (int a = 0; a < 4; a++) s[a] = srcs[(size_t)(gid0 + a) * 32 + j];

    int rslot = j >> 2;
    int c = j & 3;

    uint4 v[4][4];
#pragma unroll
    for (int a = 0; a < 4; a++)
#pragma unroll
        for (int sw = 0; sw < 4; sw++) {
            int r = __shfl(s[a], sw * 8 + rslot, 32);
            v[a][sw] = ((const uint4*)(hbf + (size_t)r * HID))[c];
        }

    float acc[4][8];
#pragma unroll
    for (int a = 0; a < 4; a++)
#pragma unroll
        for (int e = 0; e < 8; e++) acc[a][e] = 0.f;
#pragma unroll
    for (int a = 0; a < 4; a++)
#pragma unroll
        for (int sw = 0; sw < 4; sw++) {
            const uint_t* u = (const uint_t*)&v[a][sw];
#pragma unroll
            for (int e = 0; e < 8; e++)
                acc[a][e] += (e & 1) ? bfhi(u[e >> 1]) : bflo(u[e >> 1]);
        }
#pragma unroll
    for (int m = 4; m <= 16; m <<= 1)
#pragma unroll
        for (int a = 0; a < 4; a++)
#pragma unroll
            for (int e = 0; e < 8; e++) acc[a][e] += __shfl_xor(acc[a][e], m, 32);

    float o[4] = {0.f, 0.f, 0.f, 0.f};
#pragma unroll
    for (int k = 0; k < HID; k++) {
        float wv = Wh[k * HID + j];
#pragma unroll
        for (int a = 0; a < 4; a++)
            o[a] = fmaf(__shfl(acc[a][k & 7], k >> 3, 32), wv, o[a]);
    }
#pragma unroll
    for (int a = 0; a < 4; a++) agg[(size_t)(gid0 + a) * HID + j] = o[a];
}

__global__ __launch_bounds__(256) void k_mol(
        const float* __restrict__ h, const int* __restrict__ lsc,
        float* __restrict__ out) {
    int m = blockIdx.x;
    int g = threadIdx.x >> 5;
    int j = threadIdx.x & 31;
    float acc = 0.f;
    for (int i = g; i < MAXATOMS; i += 8) {
        int idx = lsc[m * MAXATOMS + i];
        if (idx > 0) acc += h[(size_t)(idx - 1) * HID + j];
    }
    __shared__ float red[8][33];
    red[g][j] = acc;
    __syncthreads();
    if (g == 0) {
        float s = red[0][j] + red[1][j] + red[2][j] + red[3][j]
                + red[4][j] + red[5][j] + red[6][j] + red[7][j];
        out[m * HID + j] = s;
    }
}

extern "C" void kernel_launch(void* const* d_in, const int* in_sizes, int n_in,
                              void* d_out, int out_size, void* d_ws, size_t ws_size,
                              hipStream_t stream) {
    (void)in_sizes; (void)n_in; (void)out_size; (void)ws_size;
    const float* tf  = (const float*)d_in[0];
    const float* fdg = (const float*)d_in[1];
    const float* rij = (const float*)d_in[2];
    const int*   bsc = (const int*)d_in[3];
    const int*   lsc = (const int*)d_in[4];
    const int*   su  = (const int*)d_in[5];
    const int*   sul = (const int*)d_in[6];
    const float* Wia = (const float*)d_in[7];
    const float* Wib = (const float*)d_in[8];
    const float* Wh  = (const float*)d_in[9];
    const float* gWz = (const float*)d_in[10];
    const float* gWr = (const float*)d_in[11];
    const float* gWh = (const float*)d_in[12];
    const float* gbz = (const float*)d_in[13];
    const float* gbr = (const float*)d_in[14];
    const float* gbh = (const float*)d_in[15];
    float* out = (float*)d_out;

    char* ws = (char*)d_ws;
    const size_t HBYTES = (size_t)NATOMS * HID * 4;                   // 32 MB
    const size_t WSPLITB = 36 * 2 * 512 * 2;                          // 72 KB
    const size_t HBFBYTES = ((size_t)(NATOMS + 1) * HID * 2 + 255) & ~(size_t)255;
    const size_t SRCSBYTES = (size_t)NATOMS * 32 * 4;                 // 32 MB
    float* h   = (float*)ws;
    float* agg = (float*)(ws + HBYTES);
    ushort_t* wsplit = (ushort_t*)(ws + 2 * HBYTES);
    ushort_t* hbf = (ushort_t*)(ws + 2 * HBYTES + WSPLITB);
    int* srcs = (int*)(ws + 2 * HBYTES + WSPLITB + HBFBYTES);
    uint4* rec = (uint4*)(ws + 2 * HBYTES + WSPLITB + HBFBYTES + SRCSBYTES);

    dim3 igrid(NATOMS / 16);                   // 15625
    dim3 ggrid((NATOMS + 63) / 64);            // 3907
    dim3 agrid((NATOMS / 4 + 7) / 8);          // 7813

    k_prep32<<<NPAIRS / 256, 256, 0, stream>>>(fdg, rij, su, sul, rec);
    k_prep_w<<<9, 256, 0, stream>>>(gWz, gWr, gWh, wsplit);
    k_init_rec<<<igrid, 256, 0, stream>>>(tf, bsc, rec, Wia, Wib, Wh,
                                          h, agg, srcs, hbf);

    for (int d = 0; d < 3; d++) {
        ushort_t* hbf_w = (d < 2) ? hbf : nullptr;
        k_gru_mfma<<<ggrid, 256, 0, stream>>>(
            h, hbf_w, agg, wsplit + (size_t)d * 12288,
            gbz + d * HID, gbr + d * HID, gbh + d * HID);
        if (d < 2)
            k_agg4<<<agrid, 256, 0, stream>>>(hbf, srcs, Wh, agg);
    }
    k_mol<<<NMOL, 256, 0, stream>>>(h, lsc, out);
}